// Round 1
// baseline (948.526 us; speedup 1.0000x reference)
//
#include <hip/hip_runtime.h>
#include <stdint.h>

#define N_NODES 50000
#define N_EDGES 800000
#define HIDDEN  64
#define EDGE_F  32
#define CAT     160   // 2H + F
#define CAT2    128   // 2H

typedef __attribute__((ext_vector_type(8))) short          bf16x8;
typedef __attribute__((ext_vector_type(4))) float          f32x4;
typedef __attribute__((ext_vector_type(4))) unsigned short u16x4;

// RNE fp32 -> bf16
static __device__ __forceinline__ unsigned short f2bf(float f) {
  unsigned int u = __builtin_bit_cast(unsigned int, f);
  unsigned int r = (u + 0x7fffu + ((u >> 16) & 1u)) >> 16;
  return (unsigned short)r;
}

// ---------------- prep: weights -> bf16, transposed (n-major, k-contig) ----------
__global__ void prep_weights_kernel(const float* __restrict__ Wffw,
                                    const float* __restrict__ Wf,
                                    const float* __restrict__ Ws,
                                    unsigned short* __restrict__ WtF,   // [160][160] (n,k)
                                    unsigned short* __restrict__ Wfs) { // [128][128] (n,k); n<64 = f, n>=64 = s
  int i = blockIdx.x * 256 + threadIdx.x;
  if (i < CAT * CAT) {
    int n = i / CAT, k = i % CAT;
    WtF[i] = f2bf(Wffw[k * CAT + n]);
  }
  if (i < CAT2 * CAT2) {
    int n = i / CAT2, k = i % CAT2;
    float v = (n < HIDDEN) ? Wf[k * HIDDEN + n] : Ws[k * HIDDEN + (n - HIDDEN)];
    Wfs[i] = f2bf(v);
  }
}

// ---------------- z_node = z (residual base) ----------------
__global__ void init_znode_kernel(const float* __restrict__ z, float* __restrict__ out) {
  int i = blockIdx.x * 256 + threadIdx.x;
  ((f32x4*)out)[i] = ((const f32x4*)z)[i];
}

// ---------------- edge MLP: z_edge = relu(cat(z_src,z_dst,ea) @ W + b) ----------
#define XS_LD 168  // 160 + 8 pad (keeps 16B alignment, breaks pow2 bank stride)
__global__ __launch_bounds__(256) void edge_mlp_kernel(
    const float* __restrict__ z, const float* __restrict__ ea,
    const int* __restrict__ ei, const unsigned short* __restrict__ WtF,
    const float* __restrict__ bffw, float* __restrict__ zedge) {
  __shared__ __align__(16) unsigned short Xs[64 * XS_LD];
  const int tid = threadIdx.x;
  const int eb  = blockIdx.x * 64;

  // stage z_src (cols 0..63) | z_dst (cols 64..127): 64 edges x 32 float4-chunks
  #pragma unroll
  for (int i = 0; i < 8; ++i) {
    int tau = tid + 256 * i;
    int el  = tau >> 5;
    int c   = tau & 31;
    int e   = eb + el;
    int node = (c < 16) ? ei[e] : ei[N_EDGES + e];  // src first, then dst
    int cc  = c & 15;
    f32x4 v = *(const f32x4*)&z[node * HIDDEN + cc * 4];
    u16x4 o = { f2bf(v[0]), f2bf(v[1]), f2bf(v[2]), f2bf(v[3]) };
    *(u16x4*)&Xs[el * XS_LD + ((c < 16) ? 0 : HIDDEN) + cc * 4] = o;
  }
  // stage edge_attr (cols 128..159): 64 edges x 8 chunks
  #pragma unroll
  for (int i = 0; i < 2; ++i) {
    int tau = tid + 256 * i;
    int el  = tau >> 3;
    int c   = tau & 7;
    int e   = eb + el;
    f32x4 v = *(const f32x4*)&ea[e * EDGE_F + c * 4];
    u16x4 o = { f2bf(v[0]), f2bf(v[1]), f2bf(v[2]), f2bf(v[3]) };
    *(u16x4*)&Xs[el * XS_LD + 2 * HIDDEN + c * 4] = o;
  }
  __syncthreads();

  const int w    = tid >> 6;
  const int lane = tid & 63;
  const int ln   = lane & 15;
  const int q    = lane >> 4;
  const int mg   = w & 1;    // edge group: [mg*32, mg*32+32)
  const int nh   = w >> 1;   // col half: [nh*80, nh*80+80)

  f32x4 acc[5][2];
  #pragma unroll
  for (int t = 0; t < 5; ++t) {
    acc[t][0] = f32x4{0.f, 0.f, 0.f, 0.f};
    acc[t][1] = f32x4{0.f, 0.f, 0.f, 0.f};
  }

  #pragma unroll
  for (int ks = 0; ks < 5; ++ks) {
    const int k0 = ks * 32 + q * 8;
    bf16x8 a0 = *(const bf16x8*)&Xs[(mg * 32 + ln) * XS_LD + k0];
    bf16x8 a1 = *(const bf16x8*)&Xs[(mg * 32 + 16 + ln) * XS_LD + k0];
    #pragma unroll
    for (int t = 0; t < 5; ++t) {
      int n = nh * 80 + t * 16 + ln;
      bf16x8 b = *(const bf16x8*)&WtF[n * CAT + k0];
      acc[t][0] = __builtin_amdgcn_mfma_f32_16x16x32_bf16(a0, b, acc[t][0], 0, 0, 0);
      acc[t][1] = __builtin_amdgcn_mfma_f32_16x16x32_bf16(a1, b, acc[t][1], 0, 0, 0);
    }
  }

  #pragma unroll
  for (int t = 0; t < 5; ++t) {
    int n = nh * 80 + t * 16 + ln;
    float bias = bffw[n];
    #pragma unroll
    for (int ms = 0; ms < 2; ++ms) {
      #pragma unroll
      for (int r = 0; r < 4; ++r) {
        int m = mg * 32 + ms * 16 + q * 4 + r;
        float y = acc[t][ms][r] + bias;
        zedge[(eb + m) * CAT + n] = fmaxf(y, 0.0f);
      }
    }
  }
}

// ---------------- CGConv: msg = sigmoid(m@Wf+bf) * softplus(m@Ws+bs); scatter ----
#define XC_LD 136  // 128 + 8 pad
__global__ __launch_bounds__(256) void cgconv_kernel(
    const float* __restrict__ z, const int* __restrict__ ei,
    const unsigned short* __restrict__ Wfs,
    const float* __restrict__ bfv, const float* __restrict__ bsv,
    float* __restrict__ znode) {
  __shared__ __align__(16) unsigned short Xs[64 * XC_LD];
  const int tid = threadIdx.x;
  const int eb  = blockIdx.x * 64;

  // stage z_dst (cols 0..63) | z_src (cols 64..127)  [m = cat(x_i, x_j)]
  #pragma unroll
  for (int i = 0; i < 8; ++i) {
    int tau = tid + 256 * i;
    int el  = tau >> 5;
    int c   = tau & 31;
    int e   = eb + el;
    int node = (c < 16) ? ei[N_EDGES + e] : ei[e];  // dst first, then src
    int cc  = c & 15;
    f32x4 v = *(const f32x4*)&z[node * HIDDEN + cc * 4];
    u16x4 o = { f2bf(v[0]), f2bf(v[1]), f2bf(v[2]), f2bf(v[3]) };
    *(u16x4*)&Xs[el * XC_LD + ((c < 16) ? 0 : HIDDEN) + cc * 4] = o;
  }
  __syncthreads();

  const int w    = tid >> 6;
  const int lane = tid & 63;
  const int ln   = lane & 15;
  const int q    = lane >> 4;
  const int mg   = w & 1;   // edge group
  const int np   = w >> 1;  // h-cols [np*32, np*32+32)

  f32x4 accF[2][2], accS[2][2];
  #pragma unroll
  for (int tt = 0; tt < 2; ++tt) {
    accF[tt][0] = f32x4{0.f, 0.f, 0.f, 0.f};
    accF[tt][1] = f32x4{0.f, 0.f, 0.f, 0.f};
    accS[tt][0] = f32x4{0.f, 0.f, 0.f, 0.f};
    accS[tt][1] = f32x4{0.f, 0.f, 0.f, 0.f};
  }

  #pragma unroll
  for (int ks = 0; ks < 4; ++ks) {
    const int k0 = ks * 32 + q * 8;
    bf16x8 a0 = *(const bf16x8*)&Xs[(mg * 32 + ln) * XC_LD + k0];
    bf16x8 a1 = *(const bf16x8*)&Xs[(mg * 32 + 16 + ln) * XC_LD + k0];
    #pragma unroll
    for (int tt = 0; tt < 2; ++tt) {
      int n = np * 32 + tt * 16 + ln;
      bf16x8 bF = *(const bf16x8*)&Wfs[n * CAT2 + k0];
      bf16x8 bS = *(const bf16x8*)&Wfs[(HIDDEN + n) * CAT2 + k0];
      accF[tt][0] = __builtin_amdgcn_mfma_f32_16x16x32_bf16(a0, bF, accF[tt][0], 0, 0, 0);
      accF[tt][1] = __builtin_amdgcn_mfma_f32_16x16x32_bf16(a1, bF, accF[tt][1], 0, 0, 0);
      accS[tt][0] = __builtin_amdgcn_mfma_f32_16x16x32_bf16(a0, bS, accS[tt][0], 0, 0, 0);
      accS[tt][1] = __builtin_amdgcn_mfma_f32_16x16x32_bf16(a1, bS, accS[tt][1], 0, 0, 0);
    }
  }

  #pragma unroll
  for (int tt = 0; tt < 2; ++tt) {
    int h = np * 32 + tt * 16 + ln;
    float bf_ = bfv[h];
    float bs_ = bsv[h];
    #pragma unroll
    for (int ms = 0; ms < 2; ++ms) {
      #pragma unroll
      for (int r = 0; r < 4; ++r) {
        int m = mg * 32 + ms * 16 + q * 4 + r;
        int e = eb + m;
        int d = ei[N_EDGES + e];
        float xf  = accF[tt][ms][r] + bf_;
        float xs  = accS[tt][ms][r] + bs_;
        float sig = 1.0f / (1.0f + __expf(-xf));
        float sp  = (xs > 20.0f) ? xs : log1pf(__expf(xs));
        atomicAdd(&znode[d * HIDDEN + h], sig * sp);
      }
    }
  }
}

extern "C" void kernel_launch(void* const* d_in, const int* in_sizes, int n_in,
                              void* d_out, int out_size, void* d_ws, size_t ws_size,
                              hipStream_t stream) {
  const float* z    = (const float*)d_in[0];
  const float* ea   = (const float*)d_in[1];
  const int*   ei   = (const int*)d_in[2];
  const float* Wffw = (const float*)d_in[3];
  const float* bffw = (const float*)d_in[4];
  const float* Wf   = (const float*)d_in[5];
  const float* bf_  = (const float*)d_in[6];
  const float* Ws   = (const float*)d_in[7];
  const float* bs_  = (const float*)d_in[8];

  float* znode = (float*)d_out;                       // [N_NODES, 64]
  float* zedge = znode + (size_t)N_NODES * HIDDEN;    // [N_EDGES, 160]

  unsigned short* WtF = (unsigned short*)d_ws;        // 160*160 bf16
  unsigned short* Wfs = WtF + CAT * CAT;              // 128*128 bf16

  prep_weights_kernel<<<(CAT * CAT + 255) / 256, 256, 0, stream>>>(Wffw, Wf, Ws, WtF, Wfs);
  init_znode_kernel<<<(N_NODES * HIDDEN / 4 + 255) / 256, 256, 0, stream>>>(z, znode);
  edge_mlp_kernel<<<N_EDGES / 64, 256, 0, stream>>>(z, ea, ei, WtF, bffw, zedge);
  cgconv_kernel<<<N_EDGES / 64, 256, 0, stream>>>(z, ei, Wfs, bf_, bs_, znode);
}

// Round 2
// 876.972 us; speedup vs baseline: 1.0816x; 1.0816x over previous
//
#include <hip/hip_runtime.h>
#include <stdint.h>

#define N_NODES 50000
#define N_EDGES 800000
#define HIDDEN  64
#define EDGE_F  32
#define CAT     160   // 2H + F
#define CAT2    128   // 2H

typedef __attribute__((ext_vector_type(8))) short          bf16x8;
typedef __attribute__((ext_vector_type(4))) float          f32x4;
typedef __attribute__((ext_vector_type(4))) unsigned short u16x4;

// RNE fp32 -> bf16
static __device__ __forceinline__ unsigned short f2bf(float f) {
  unsigned int u = __builtin_bit_cast(unsigned int, f);
  return (unsigned short)((u + 0x7fffu + ((u >> 16) & 1u)) >> 16);
}

// ---------------- prep: znode = z; zb = bf16(z); weights -> bf16 transposed ----
__global__ __launch_bounds__(256) void prep_kernel(
    const float* __restrict__ z, const float* __restrict__ Wffw,
    const float* __restrict__ Wf, const float* __restrict__ Ws,
    float* __restrict__ znode, unsigned short* __restrict__ zb,
    unsigned short* __restrict__ WtF,   // [160][160] (n-major, k-contig)
    unsigned short* __restrict__ Wfs) { // [128][128]; rows 0..63 = f, 64..127 = s
  int i = blockIdx.x * 256 + threadIdx.x;
  if (i < N_NODES * HIDDEN / 4) {
    f32x4 v = ((const f32x4*)z)[i];
    ((f32x4*)znode)[i] = v;
    u16x4 o = { f2bf(v[0]), f2bf(v[1]), f2bf(v[2]), f2bf(v[3]) };
    ((u16x4*)zb)[i] = o;
  }
  if (i < CAT * CAT) {
    int n = i / CAT, k = i % CAT;
    WtF[i] = f2bf(Wffw[k * CAT + n]);
  }
  if (i < CAT2 * CAT2) {
    int n = i / CAT2, k = i % CAT2;
    float v = (n < HIDDEN) ? Wf[k * HIDDEN + n] : Ws[k * HIDDEN + (n - HIDDEN)];
    Wfs[i] = f2bf(v);
  }
}

// ---------------- fused per-edge kernel: edge MLP GEMM + CGConv GEMM + scatter ----
// LDS: Zs[64][136] bf16: cols 0..63 = z_src, 64..127 = z_dst (stride 136 -> bank
// stride 68 == 4 mod 32, odd multiplier -> even 8-phase spread for b128 reads).
// Ea[64][40] bf16: edge_attr.
#define ZS_LD 136
#define EA_LD 40

__global__ __launch_bounds__(256) void fused_edge_kernel(
    const unsigned short* __restrict__ zb, const float* __restrict__ ea,
    const int* __restrict__ ei,
    const unsigned short* __restrict__ WtF, const unsigned short* __restrict__ Wfs,
    const float* __restrict__ bffw, const float* __restrict__ bfv,
    const float* __restrict__ bsv,
    float* __restrict__ zedge, float* __restrict__ znode) {
  __shared__ __align__(16) unsigned short Zs[64 * ZS_LD];
  __shared__ __align__(16) unsigned short Ea[64 * EA_LD];
  const int tid = threadIdx.x;
  const int eb  = blockIdx.x * 64;

  // stage z rows (bf16, no conversion): 64 edges x 2 halves x 8 chunks of 16B
  #pragma unroll
  for (int i = 0; i < 4; ++i) {
    int tau  = tid + 256 * i;
    int el   = tau >> 4;
    int c    = tau & 15;
    int half = c >> 3;      // 0 = src, 1 = dst
    int cc   = c & 7;
    int e    = eb + el;
    int node = half ? ei[N_EDGES + e] : ei[e];
    bf16x8 v = *(const bf16x8*)&zb[node * HIDDEN + cc * 8];
    *(bf16x8*)&Zs[el * ZS_LD + half * 64 + cc * 8] = v;
  }
  // stage edge_attr (convert fp32->bf16): 64 edges x 8 f32x4 chunks
  #pragma unroll
  for (int i = 0; i < 2; ++i) {
    int tau = tid + 256 * i;
    int el  = tau >> 3;
    int c   = tau & 7;
    f32x4 v = __builtin_nontemporal_load((const f32x4*)&ea[(eb + el) * EDGE_F + c * 4]);
    u16x4 o = { f2bf(v[0]), f2bf(v[1]), f2bf(v[2]), f2bf(v[3]) };
    *(u16x4*)&Ea[el * EA_LD + c * 4] = o;
  }
  __syncthreads();

  const int w    = tid >> 6;
  const int lane = tid & 63;
  const int ln   = lane & 15;
  const int q    = lane >> 4;
  const int mg   = w & 1;    // edge rows [mg*32, +32)
  const int nh   = w >> 1;   // edge-MLP col half [nh*80, +80); CG col half [nh*32, +32)

  // ============ edge MLP: z_edge = relu(cat(src,dst,ea) @ Wffw + b) ============
  {
    f32x4 acc[5][2];
    #pragma unroll
    for (int t = 0; t < 5; ++t) {
      acc[t][0] = f32x4{0.f, 0.f, 0.f, 0.f};
      acc[t][1] = f32x4{0.f, 0.f, 0.f, 0.f};
    }
    #pragma unroll
    for (int ks = 0; ks < 5; ++ks) {
      bf16x8 a0, a1;
      if (ks < 4) {
        int off = ks * 32 + q * 8;
        a0 = *(const bf16x8*)&Zs[(mg * 32 + ln) * ZS_LD + off];
        a1 = *(const bf16x8*)&Zs[(mg * 32 + 16 + ln) * ZS_LD + off];
      } else {
        int off = q * 8;
        a0 = *(const bf16x8*)&Ea[(mg * 32 + ln) * EA_LD + off];
        a1 = *(const bf16x8*)&Ea[(mg * 32 + 16 + ln) * EA_LD + off];
      }
      int k0 = ks * 32 + q * 8;
      #pragma unroll
      for (int t = 0; t < 5; ++t) {
        int n = nh * 80 + t * 16 + ln;
        bf16x8 b = *(const bf16x8*)&WtF[n * CAT + k0];
        acc[t][0] = __builtin_amdgcn_mfma_f32_16x16x32_bf16(a0, b, acc[t][0], 0, 0, 0);
        acc[t][1] = __builtin_amdgcn_mfma_f32_16x16x32_bf16(a1, b, acc[t][1], 0, 0, 0);
      }
    }
    #pragma unroll
    for (int t = 0; t < 5; ++t) {
      int n = nh * 80 + t * 16 + ln;
      float bias = bffw[n];
      #pragma unroll
      for (int ms = 0; ms < 2; ++ms) {
        #pragma unroll
        for (int r = 0; r < 4; ++r) {
          int m = mg * 32 + ms * 16 + q * 4 + r;
          float y = fmaxf(acc[t][ms][r] + bias, 0.0f);
          __builtin_nontemporal_store(y, &zedge[(eb + m) * CAT + n]);
        }
      }
    }
  }

  // ============ CGConv: msg = sig(cat(dst,src)@Wf+bf)*softplus(...Ws+bs) ======
  {
    f32x4 accF[2][2], accS[2][2];
    #pragma unroll
    for (int tt = 0; tt < 2; ++tt) {
      accF[tt][0] = f32x4{0.f, 0.f, 0.f, 0.f};
      accF[tt][1] = f32x4{0.f, 0.f, 0.f, 0.f};
      accS[tt][0] = f32x4{0.f, 0.f, 0.f, 0.f};
      accS[tt][1] = f32x4{0.f, 0.f, 0.f, 0.f};
    }
    // logical k = [dst(0..63) | src(64..127)]; physical Zs = [src | dst]
    const int cgoff[4] = {64, 96, 0, 32};
    #pragma unroll
    for (int ks = 0; ks < 4; ++ks) {
      int off = cgoff[ks] + q * 8;
      bf16x8 a0 = *(const bf16x8*)&Zs[(mg * 32 + ln) * ZS_LD + off];
      bf16x8 a1 = *(const bf16x8*)&Zs[(mg * 32 + 16 + ln) * ZS_LD + off];
      int k0 = ks * 32 + q * 8;
      #pragma unroll
      for (int tt = 0; tt < 2; ++tt) {
        int n = nh * 32 + tt * 16 + ln;
        bf16x8 bF = *(const bf16x8*)&Wfs[n * CAT2 + k0];
        bf16x8 bS = *(const bf16x8*)&Wfs[(HIDDEN + n) * CAT2 + k0];
        accF[tt][0] = __builtin_amdgcn_mfma_f32_16x16x32_bf16(a0, bF, accF[tt][0], 0, 0, 0);
        accF[tt][1] = __builtin_amdgcn_mfma_f32_16x16x32_bf16(a1, bF, accF[tt][1], 0, 0, 0);
        accS[tt][0] = __builtin_amdgcn_mfma_f32_16x16x32_bf16(a0, bS, accS[tt][0], 0, 0, 0);
        accS[tt][1] = __builtin_amdgcn_mfma_f32_16x16x32_bf16(a1, bS, accS[tt][1], 0, 0, 0);
      }
    }
    int dc[2][4];
    #pragma unroll
    for (int ms = 0; ms < 2; ++ms)
      #pragma unroll
      for (int r = 0; r < 4; ++r)
        dc[ms][r] = ei[N_EDGES + eb + mg * 32 + ms * 16 + q * 4 + r];

    #pragma unroll
    for (int tt = 0; tt < 2; ++tt) {
      int h = nh * 32 + tt * 16 + ln;
      float bf_ = bfv[h];
      float bs_ = bsv[h];
      #pragma unroll
      for (int ms = 0; ms < 2; ++ms) {
        #pragma unroll
        for (int r = 0; r < 4; ++r) {
          float xf  = accF[tt][ms][r] + bf_;
          float xs  = accS[tt][ms][r] + bs_;
          float sig = 1.0f / (1.0f + __expf(-xf));
          float sp  = (xs > 20.0f) ? xs : log1pf(__expf(xs));
          atomicAdd(&znode[dc[ms][r] * HIDDEN + h], sig * sp);
        }
      }
    }
  }
}

extern "C" void kernel_launch(void* const* d_in, const int* in_sizes, int n_in,
                              void* d_out, int out_size, void* d_ws, size_t ws_size,
                              hipStream_t stream) {
  const float* z    = (const float*)d_in[0];
  const float* ea   = (const float*)d_in[1];
  const int*   ei   = (const int*)d_in[2];
  const float* Wffw = (const float*)d_in[3];
  const float* bffw = (const float*)d_in[4];
  const float* Wf   = (const float*)d_in[5];
  const float* bf_  = (const float*)d_in[6];
  const float* Ws   = (const float*)d_in[7];
  const float* bs_  = (const float*)d_in[8];

  float* znode = (float*)d_out;                       // [N_NODES, 64]
  float* zedge = znode + (size_t)N_NODES * HIDDEN;    // [N_EDGES, 160]

  unsigned short* zb  = (unsigned short*)d_ws;        // 50000*64 bf16 (6.4 MB)
  unsigned short* WtF = zb + (size_t)N_NODES * HIDDEN;
  unsigned short* Wfs = WtF + CAT * CAT;

  prep_kernel<<<(N_NODES * HIDDEN / 4 + 255) / 256, 256, 0, stream>>>(
      z, Wffw, Wf, Ws, znode, zb, WtF, Wfs);
  fused_edge_kernel<<<N_EDGES / 64, 256, 0, stream>>>(
      zb, ea, ei, WtF, Wfs, bffw, bf_, bs_, zedge, znode);
}